// Round 5
// baseline (217.560 us; speedup 1.0000x reference)
//
#include <hip/hip_runtime.h>
#include <math.h>

// Problem constants (match reference)
constexpr int NUM_HEADS    = 32;
constexpr int NUM_KV_HEADS = 8;
constexpr int HEAD_SIZE    = 128;
constexpr int T            = 16384;
constexpr int NUM_SLOTS    = 32768;
constexpr int QD = NUM_HEADS * HEAD_SIZE;     // 4096 floats per token
constexpr int KD = NUM_KV_HEADS * HEAD_SIZE;  // 1024 floats per token
constexpr int HALF = HEAD_SIZE / 2;           // 64

// Output layout (flat float offsets in d_out, reference return order)
constexpr size_t Q_OUT  = 0;
constexpr size_t K_OUT  = (size_t)T * QD;                  //  67,108,864
constexpr size_t V_OUT  = K_OUT + (size_t)T * KD;          //  83,886,080
constexpr size_t KC_OUT = V_OUT + (size_t)T * KD;          // 100,663,296
constexpr size_t VC_OUT = KC_OUT + (size_t)NUM_SLOTS * KD; // 134,217,728

// log2(10000)/64 — for inv_freq[j] = 2^(-j * log2(10000)/64)
#define LOG2_BASE_OVER_64 0.2076205059131857f

// Native clang vector type — required by __builtin_nontemporal_*.
typedef float f4 __attribute__((ext_vector_type(4)));

__device__ __forceinline__ f4 ntload4(const float* p) {
    return __builtin_nontemporal_load((const f4*)p);
}
__device__ __forceinline__ void ntstore4(float* p, f4 v) {
    __builtin_nontemporal_store(v, (f4*)p);
}

__device__ __forceinline__ void rope4(const f4 a, const f4 b,
                                      const float* cs, const float* sn, int j0,
                                      f4& o1, f4& o2) {
    o1.x = a.x * cs[j0 + 0] - b.x * sn[j0 + 0];
    o1.y = a.y * cs[j0 + 1] - b.y * sn[j0 + 1];
    o1.z = a.z * cs[j0 + 2] - b.z * sn[j0 + 2];
    o1.w = a.w * cs[j0 + 3] - b.w * sn[j0 + 3];
    o2.x = b.x * cs[j0 + 0] + a.x * sn[j0 + 0];
    o2.y = b.y * cs[j0 + 1] + a.y * sn[j0 + 1];
    o2.z = b.z * cs[j0 + 2] + a.z * sn[j0 + 2];
    o2.w = b.w * cs[j0 + 3] + a.w * sn[j0 + 3];
}

// Kernel A: mark which cache slots get scattered into this call (byte flags).
__global__ __launch_bounds__(256) void mark_slots_kernel(
    const int* __restrict__ slot_mapping, unsigned char* __restrict__ mapped)
{
    const int i = blockIdx.x * 256 + threadIdx.x;
    if (i < T) mapped[slot_mapping[i]] = 1;
}

// Kernel B (fused): blocks [0,T) do per-token rope + outputs + mapped-row
// scatter; blocks [T, T+NUM_SLOTS) copy unmapped cache rows. The two sets
// of cache-row writes are disjoint by construction of `mapped`.
__global__ __launch_bounds__(256) void fused_rope_fill_kernel(
    const float* __restrict__ q, const float* __restrict__ k,
    const float* __restrict__ v,
    const int* __restrict__ positions, const int* __restrict__ slot_mapping,
    const float* __restrict__ k_cache, const float* __restrict__ v_cache,
    const unsigned char* __restrict__ mapped, float* __restrict__ out)
{
    const int b   = blockIdx.x;
    const int tid = threadIdx.x;

    if (b >= T) {
        // ---- cache-fill path: copy old row for unmapped slots ----
        const int slot = b - T;
        if (mapped[slot]) return;       // block-uniform branch
        const size_t row = (size_t)slot * KD;
        const f4 kv = ntload4(k_cache + row + tid * 4);
        const f4 vv = ntload4(v_cache + row + tid * 4);
        ntstore4(out + KC_OUT + row + tid * 4, kv);
        ntstore4(out + VC_OUT + row + tid * 4, vv);
        return;
    }

    // ---- token path ----
    const int tok = b;

    __shared__ float cs[HALF];
    __shared__ float sn[HALF];

    const int pos  = positions[tok];
    const int slot = slot_mapping[tok];

    if (tid < HALF) {
        // inv_freq[j] = 10000^(-2j/128) = 2^(-j*log2(10000)/64), via HW exp2.
        const float inv  = exp2f(-(float)tid * LOG2_BASE_OVER_64);
        const float freq = (float)pos * inv;
        float s, c;
        __sincosf(freq, &s, &c);
        // use precise sincosf for accuracy (fast path tested below)
        sincosf(freq, &s, &c);
        cs[tid] = c;
        sn[tid] = s;
    }
    __syncthreads();

    // ---- Q rope: 32 heads x 16 pair-quads = 512 pair-quads, 2 iters ----
    {
        const float* qrow = q + (size_t)tok * QD;
        float*       orow = out + Q_OUT + (size_t)tok * QD;
        const int head0 = tid >> 4;             // iter 0: p = tid
        const int head1 = (256 + tid) >> 4;     // iter 1: p = 256 + tid
        const int jq    = tid & 15;
        const int j0    = jq * 4;
        // issue all 4 loads first for MLP
        const f4 a0 = ntload4(qrow + head0 * 128 + j0);
        const f4 b0 = ntload4(qrow + head0 * 128 + 64 + j0);
        const f4 a1 = ntload4(qrow + head1 * 128 + j0);
        const f4 b1 = ntload4(qrow + head1 * 128 + 64 + j0);
        f4 o1, o2, o3, o4;
        rope4(a0, b0, cs, sn, j0, o1, o2);
        rope4(a1, b1, cs, sn, j0, o3, o4);
        ntstore4(orow + head0 * 128 + j0,      o1);
        ntstore4(orow + head0 * 128 + 64 + j0, o2);
        ntstore4(orow + head1 * 128 + j0,      o3);
        ntstore4(orow + head1 * 128 + 64 + j0, o4);
    }

    // ---- split phase: waves 0-1 do K rope+scatter, waves 2-3 do V ----
    if (tid < 128) {
        const int head = tid >> 4;
        const int jq   = tid & 15;
        const int j0   = jq * 4;
        const float* krow = k + (size_t)tok * KD;
        const f4 a  = ntload4(krow + head * 128 + j0);
        const f4 bk = ntload4(krow + head * 128 + 64 + j0);
        f4 o1, o2;
        rope4(a, bk, cs, sn, j0, o1, o2);
        float* korow = out + K_OUT + (size_t)tok * KD;
        ntstore4(korow + head * 128 + j0,      o1);
        ntstore4(korow + head * 128 + 64 + j0, o2);
        float* kcrow = out + KC_OUT + (size_t)slot * KD;
        ntstore4(kcrow + head * 128 + j0,      o1);
        ntstore4(kcrow + head * 128 + 64 + j0, o2);
    } else {
        const int t2 = tid - 128;               // 0..127, each handles 2 f4
        const float* vrow = v + (size_t)tok * KD;
        const f4 v0 = ntload4(vrow + t2 * 4);
        const f4 v1 = ntload4(vrow + (t2 + 128) * 4);
        float* vorow = out + V_OUT  + (size_t)tok  * KD;
        float* vcrow = out + VC_OUT + (size_t)slot * KD;
        ntstore4(vorow + t2 * 4,         v0);
        ntstore4(vorow + (t2 + 128) * 4, v1);
        ntstore4(vcrow + t2 * 4,         v0);
        ntstore4(vcrow + (t2 + 128) * 4, v1);
    }
}

extern "C" void kernel_launch(void* const* d_in, const int* in_sizes, int n_in,
                              void* d_out, int out_size, void* d_ws, size_t ws_size,
                              hipStream_t stream) {
    const float* q   = (const float*)d_in[0];
    const float* k   = (const float*)d_in[1];
    const float* v   = (const float*)d_in[2];
    const int* positions    = (const int*)d_in[3];
    const int* slot_mapping = (const int*)d_in[4];
    const float* k_cache = (const float*)d_in[5];
    const float* v_cache = (const float*)d_in[6];
    float* out = (float*)d_out;
    unsigned char* mapped = (unsigned char*)d_ws;   // NUM_SLOTS bytes = 32 KB

    (void)hipMemsetAsync(mapped, 0, (size_t)NUM_SLOTS, stream);
    mark_slots_kernel<<<(T + 255) / 256, 256, 0, stream>>>(slot_mapping, mapped);
    fused_rope_fill_kernel<<<T + NUM_SLOTS, 256, 0, stream>>>(
        q, k, v, positions, slot_mapping, k_cache, v_cache, mapped, out);
}